// Round 3
// baseline (39.329 us; speedup 1.0000x reference)
//
#include <hip/hip_runtime.h>

#define IMG_H 4096
#define IMG_W 6144
#define BORDER_VAL 1e20f

#define ROWS 8                      // output rows per thread
#define COLS 8                      // output cols per thread
#define TPB  256
#define GX   (IMG_W / (TPB * COLS)) // 3 column groups
#define GY   (IMG_H / ROWS)         // 512 row groups
#define NBLK (GX * GY)              // 1536 blocks
#define BAND (GY / 8)               // 64 row-groups per XCD band

typedef float v4f __attribute__((ext_vector_type(4)));

// Each thread: 8 cols x 8 rows of output. Loads 10 input rows as
// 2x dwordx4 + 2 edge scalars each (0.5 mem-instr per output).
// Vertical reuse in registers (amplification 10/8). XCD band swizzle
// keeps the 2-row halo overlap L2-local. Output stored nontemporal so
// it doesn't evict the input from L2/L3.
__global__ __launch_bounds__(256) void erode3x3_kernel(
    const float* __restrict__ img,
    const float* __restrict__ se,
    float* __restrict__ out)
{
    const int v    = blockIdx.x;
    const int xcd  = v & 7;                  // HW round-robins blocks over XCDs
    const int slot = v >> 3;
    const int gy   = xcd * BAND + slot / GX; // contiguous row band per XCD
    const int gx   = slot - (slot / GX) * GX;

    const int j0 = (gx * TPB + (int)threadIdx.x) * COLS; // first output col
    const int r0 = gy * ROWS;                            // first output row

    const float s00 = se[0], s01 = se[1], s02 = se[2];
    const float s10 = se[3], s11 = se[4], s12 = se[5];
    const float s20 = se[6], s21 = se[7], s22 = se[8];

    // vbuf[p][c]: input row r0 + p - 1, columns j0-1 .. j0+8  (c = 0..9)
    float vbuf[ROWS + 2][COLS + 2];
    #pragma unroll
    for (int p = 0; p < ROWS + 2; ++p) {
        const int r = r0 + p - 1;
        if (r < 0 || r >= IMG_H) {           // wave-uniform branch
            #pragma unroll
            for (int c = 0; c < COLS + 2; ++c) vbuf[p][c] = BORDER_VAL;
        } else {
            const float* __restrict__ row = img + (size_t)r * IMG_W;
            const v4f a = *reinterpret_cast<const v4f*>(row + j0);
            const v4f b = *reinterpret_cast<const v4f*>(row + j0 + 4);
            vbuf[p][1] = a.x; vbuf[p][2] = a.y; vbuf[p][3] = a.z; vbuf[p][4] = a.w;
            vbuf[p][5] = b.x; vbuf[p][6] = b.y; vbuf[p][7] = b.z; vbuf[p][8] = b.w;
            vbuf[p][0]        = (j0 > 0)            ? row[j0 - 1]    : BORDER_VAL;
            vbuf[p][COLS + 1] = (j0 + COLS < IMG_W) ? row[j0 + COLS] : BORDER_VAL;
        }
    }

    #pragma unroll
    for (int rr = 0; rr < ROWS; ++rr) {
        float o[COLS];
        #pragma unroll
        for (int k = 0; k < COLS; ++k) {
            float m;
            m =          vbuf[rr + 0][k + 0] - s00;
            m = fminf(m, vbuf[rr + 0][k + 1] - s01);
            m = fminf(m, vbuf[rr + 0][k + 2] - s02);
            m = fminf(m, vbuf[rr + 1][k + 0] - s10);
            m = fminf(m, vbuf[rr + 1][k + 1] - s11);
            m = fminf(m, vbuf[rr + 1][k + 2] - s12);
            m = fminf(m, vbuf[rr + 2][k + 0] - s20);
            m = fminf(m, vbuf[rr + 2][k + 1] - s21);
            m = fminf(m, vbuf[rr + 2][k + 2] - s22);
            o[k] = m;
        }
        float* dst = out + (size_t)(r0 + rr) * IMG_W + j0;
        v4f lo; lo.x = o[0]; lo.y = o[1]; lo.z = o[2]; lo.w = o[3];
        v4f hi; hi.x = o[4]; hi.y = o[5]; hi.z = o[6]; hi.w = o[7];
        __builtin_nontemporal_store(lo, reinterpret_cast<v4f*>(dst));
        __builtin_nontemporal_store(hi, reinterpret_cast<v4f*>(dst + 4));
    }
}

extern "C" void kernel_launch(void* const* d_in, const int* in_sizes, int n_in,
                              void* d_out, int out_size, void* d_ws, size_t ws_size,
                              hipStream_t stream)
{
    const float* img = (const float*)d_in[0];
    const float* se  = (const float*)d_in[1];
    float* out       = (float*)d_out;

    dim3 block(TPB, 1, 1);
    dim3 grid(NBLK, 1, 1);
    erode3x3_kernel<<<grid, block, 0, stream>>>(img, se, out);
}